// Round 1
// baseline (1001.259 us; speedup 1.0000x reference)
//
#include <hip/hip_runtime.h>
#include <hip/hip_bf16.h>

// Problem constants
#define B_  1024
#define L_  2
#define D_  1024
#define F_  32768
#define K1  (L_*D_)      // 2048 — encoder K
#define M_  B_           // 1024
#define N2  (L_*D_)      // 2048 — decoder N (both layers fused)
#define SPLITK 4
#define KC  (F_/SPLITK)  // 8192 per split-K chunk

// Tile config
#define BM 128
#define BN 128
#define BK 32
#define LDK 40           // BK + 8 bf16 pad -> 80B row stride (16B aligned)

typedef __attribute__((ext_vector_type(4))) float  f32x4;
typedef __attribute__((ext_vector_type(8))) __bf16 bf16x8;
typedef __attribute__((ext_vector_type(4))) __bf16 bf16x4;

// ---------------------------------------------------------------------------
// GEMM1: f = relu(x[M,K1] @ W_enc[K1,F] + b_enc), output bf16
// ---------------------------------------------------------------------------
__global__ __launch_bounds__(256, 2) void gemm1_enc(
    const float* __restrict__ X, const float* __restrict__ We,
    const float* __restrict__ be, __bf16* __restrict__ Fout)
{
    __shared__ __bf16 As[BM][LDK];
    __shared__ __bf16 Bs[BN][LDK];

    const int tid = threadIdx.x;
    const int m0 = blockIdx.x * BM;   // m fastest: 8 m-blocks share a W_enc panel
    const int n0 = blockIdx.y * BN;

    const int lane = tid & 63;
    const int w  = tid >> 6;
    const int wr = w >> 1, wc = w & 1;
    const int g  = lane >> 4;         // k-group 0..3
    const int r  = lane & 15;         // row (A) / col (B,C)

    // staging indices
    const int a_row = tid >> 3;       // 0..31 (+32*p)
    const int a_c4  = tid & 7;        // float4 col within BK
    const int b_kb  = tid >> 5;       // 0..7
    const int b_nb  = tid & 31;       // 0..31

    f32x4 acc[4][4] = {};

    f32x4 aP[4];
    f32x4 bP[4];

    const float* Aptr = X + (size_t)m0 * K1;
    const float* Bptr = We + n0;

    auto loadA = [&](int k0) {
        #pragma unroll
        for (int p = 0; p < 4; ++p) {
            int row = a_row + 32*p;
            aP[p] = *(const f32x4*)(Aptr + (size_t)row*K1 + k0 + a_c4*4);
        }
    };
    auto loadB = [&](int k0) {
        #pragma unroll
        for (int i = 0; i < 4; ++i) {
            bP[i] = *(const f32x4*)(Bptr + (size_t)(k0 + b_kb*4 + i)*F_ + b_nb*4);
        }
    };
    auto stageA = [&]() {
        #pragma unroll
        for (int p = 0; p < 4; ++p) {
            int row = a_row + 32*p;
            bf16x4 v;
            v[0] = (__bf16)aP[p][0]; v[1] = (__bf16)aP[p][1];
            v[2] = (__bf16)aP[p][2]; v[3] = (__bf16)aP[p][3];
            *(bf16x4*)&As[row][a_c4*4] = v;
        }
    };
    auto stageB = [&]() {
        #pragma unroll
        for (int j = 0; j < 4; ++j) {
            bf16x4 v;
            v[0] = (__bf16)bP[0][j]; v[1] = (__bf16)bP[1][j];
            v[2] = (__bf16)bP[2][j]; v[3] = (__bf16)bP[3][j];
            *(bf16x4*)&Bs[b_nb*4 + j][b_kb*4] = v;
        }
    };

    loadA(0); loadB(0);
    for (int k0 = 0; k0 < K1; k0 += BK) {
        stageA(); stageB();
        __syncthreads();
        if (k0 + BK < K1) { loadA(k0 + BK); loadB(k0 + BK); }

        bf16x8 a[4], b[4];
        #pragma unroll
        for (int i = 0; i < 4; ++i)
            a[i] = *(const bf16x8*)&As[wr*64 + i*16 + r][g*8];
        #pragma unroll
        for (int j = 0; j < 4; ++j)
            b[j] = *(const bf16x8*)&Bs[wc*64 + j*16 + r][g*8];
        #pragma unroll
        for (int i = 0; i < 4; ++i)
            #pragma unroll
            for (int j = 0; j < 4; ++j)
                acc[i][j] = __builtin_amdgcn_mfma_f32_16x16x32_bf16(
                    a[i], b[j], acc[i][j], 0, 0, 0);
        __syncthreads();
    }

    // epilogue: relu(acc + b_enc[col]) -> bf16
    #pragma unroll
    for (int j = 0; j < 4; ++j) {
        int col = n0 + wc*64 + j*16 + r;
        float bv = be[col];
        #pragma unroll
        for (int i = 0; i < 4; ++i) {
            #pragma unroll
            for (int v = 0; v < 4; ++v) {
                int row = m0 + wr*64 + i*16 + g*4 + v;
                float z = acc[i][j][v] + bv;
                z = z > 0.f ? z : 0.f;
                Fout[(size_t)row * F_ + col] = (__bf16)z;
            }
        }
    }
}

// ---------------------------------------------------------------------------
// GEMM2 (split-K): Cp[s] = f[M,KC-chunk] @ W_dec-chunk, fp32 partials
// B[k][n] = W_dec[n>>10][k][n&1023]
// ---------------------------------------------------------------------------
__global__ __launch_bounds__(256, 2) void gemm2_dec(
    const __bf16* __restrict__ Fin, const float* __restrict__ Wd,
    float* __restrict__ Cp)
{
    __shared__ __bf16 As[BM][LDK];
    __shared__ __bf16 Bs[BN][LDK];

    const int tid = threadIdx.x;
    const int m0 = blockIdx.x * BM;
    const int n0 = blockIdx.y * BN;
    const int s  = blockIdx.z;
    const int kbase = s * KC;

    const int lane = tid & 63;
    const int w  = tid >> 6;
    const int wr = w >> 1, wc = w & 1;
    const int g  = lane >> 4;
    const int r  = lane & 15;

    // A staging (bf16 source): 16B per thread x 2 passes
    const int a_row = tid >> 2;       // 0..63 (+64*p)
    const int a_c8  = tid & 3;        // which 8-elem chunk
    // B staging micro-tile
    const int b_kb  = tid >> 5;       // 0..7
    const int b_nb  = tid & 31;       // 0..31

    f32x4 acc[4][4] = {};

    f32x4 aP[2];    // raw 16B of bf16 (8 elems)
    f32x4 bP[4];

    const int ldec = n0 >> 10;                                  // which layer
    const float* Bptr = Wd + (size_t)ldec * F_ * D_ + (n0 & (D_-1));
    const __bf16* Aptr = Fin + (size_t)m0 * F_ + kbase;

    auto loadA = [&](int k0) {
        #pragma unroll
        for (int p = 0; p < 2; ++p) {
            int row = a_row + 64*p;
            aP[p] = *(const f32x4*)(Aptr + (size_t)row*F_ + k0 + a_c8*8);
        }
    };
    auto loadB = [&](int k0) {
        #pragma unroll
        for (int i = 0; i < 4; ++i) {
            bP[i] = *(const f32x4*)(Bptr + (size_t)(kbase + k0 + b_kb*4 + i)*D_ + b_nb*4);
        }
    };
    auto stageA = [&]() {
        #pragma unroll
        for (int p = 0; p < 2; ++p) {
            int row = a_row + 64*p;
            *(f32x4*)&As[row][a_c8*8] = aP[p];   // raw bf16 passthrough
        }
    };
    auto stageB = [&]() {
        #pragma unroll
        for (int j = 0; j < 4; ++j) {
            bf16x4 v;
            v[0] = (__bf16)bP[0][j]; v[1] = (__bf16)bP[1][j];
            v[2] = (__bf16)bP[2][j]; v[3] = (__bf16)bP[3][j];
            *(bf16x4*)&Bs[b_nb*4 + j][b_kb*4] = v;
        }
    };

    loadA(0); loadB(0);
    for (int k0 = 0; k0 < KC; k0 += BK) {
        stageA(); stageB();
        __syncthreads();
        if (k0 + BK < KC) { loadA(k0 + BK); loadB(k0 + BK); }

        bf16x8 a[4], b[4];
        #pragma unroll
        for (int i = 0; i < 4; ++i)
            a[i] = *(const bf16x8*)&As[wr*64 + i*16 + r][g*8];
        #pragma unroll
        for (int j = 0; j < 4; ++j)
            b[j] = *(const bf16x8*)&Bs[wc*64 + j*16 + r][g*8];
        #pragma unroll
        for (int i = 0; i < 4; ++i)
            #pragma unroll
            for (int j = 0; j < 4; ++j)
                acc[i][j] = __builtin_amdgcn_mfma_f32_16x16x32_bf16(
                    a[i], b[j], acc[i][j], 0, 0, 0);
        __syncthreads();
    }

    // epilogue: write fp32 partial
    #pragma unroll
    for (int j = 0; j < 4; ++j) {
        int col = n0 + wc*64 + j*16 + r;
        #pragma unroll
        for (int i = 0; i < 4; ++i) {
            #pragma unroll
            for (int v = 0; v < 4; ++v) {
                int row = m0 + wr*64 + i*16 + g*4 + v;
                Cp[((size_t)s*M_ + row)*N2 + col] = acc[i][j][v];
            }
        }
    }
}

// ---------------------------------------------------------------------------
// Reduce: out[m][n] = sum_s Cp[s][m][n] + b_dec[n]
// ---------------------------------------------------------------------------
__global__ __launch_bounds__(256) void reduce_add(
    const float* __restrict__ Cp, const float* __restrict__ bd,
    float* __restrict__ out)
{
    const size_t idx = ((size_t)blockIdx.x * 256 + threadIdx.x) * 4;
    f32x4 acc = {};
    #pragma unroll
    for (int s = 0; s < SPLITK; ++s) {
        f32x4 c = *(const f32x4*)(Cp + (size_t)s * M_ * N2 + idx);
        acc += c;
    }
    f32x4 b = *(const f32x4*)(bd + (idx & (N2 - 1)));
    *(f32x4*)(out + idx) = acc + b;
}

// ---------------------------------------------------------------------------
extern "C" void kernel_launch(void* const* d_in, const int* in_sizes, int n_in,
                              void* d_out, int out_size, void* d_ws, size_t ws_size,
                              hipStream_t stream) {
    const float* x  = (const float*)d_in[0];
    const float* We = (const float*)d_in[1];
    const float* be = (const float*)d_in[2];
    const float* Wd = (const float*)d_in[3];
    const float* bd = (const float*)d_in[4];
    float* out = (float*)d_out;

    // ws layout: f (bf16, 64MB) | Cp (fp32, SPLITK*M*N2 = 32MB)
    __bf16* f  = (__bf16*)d_ws;
    float*  Cp = (float*)((char*)d_ws + (size_t)M_ * F_ * sizeof(__bf16));

    gemm1_enc<<<dim3(M_/BM, F_/BN), 256, 0, stream>>>(x, We, be, f);
    gemm2_dec<<<dim3(M_/BM, N2/BN, SPLITK), 256, 0, stream>>>(f, Wd, Cp);
    reduce_add<<<dim3((M_*(size_t)N2)/(4*256)), 256, 0, stream>>>(Cp, bd, out);
}

// Round 2
// 979.143 us; speedup vs baseline: 1.0226x; 1.0226x over previous
//
#include <hip/hip_runtime.h>
#include <hip/hip_bf16.h>

// Problem constants
#define B_  1024
#define L_  2
#define D_  1024
#define F_  32768
#define K1  (L_*D_)      // 2048 — encoder K
#define M_  B_           // 1024
#define N2  (L_*D_)      // 2048 — decoder N (both layers fused)
#define SPLITK 4
#define KC  (F_/SPLITK)  // 8192 per split-K chunk

// Tile config
#define BM 128
#define BN 128
#define BK 32
// Padded LDS rows: 9 chunks of 16B (72 bf16 = 144 B). Chunk-slot stride
// 9 % 8 == 1 -> consecutive n/m rows cycle all 8 chunk-columns -> no conflicts.
#define ROWE 72          // elements per padded row

typedef __attribute__((ext_vector_type(4))) float  f32x4;
typedef __attribute__((ext_vector_type(8))) __bf16 bf16x8;

__device__ inline void glds16(const void* g, void* l) {
    __builtin_amdgcn_global_load_lds(
        (const __attribute__((address_space(1))) unsigned int*)g,
        (__attribute__((address_space(3))) unsigned int*)l, 16, 0, 0);
}

// ---------------------------------------------------------------------------
// GEMM1: f = relu(x[M,K1] @ W_enc[K1,F] + b_enc), output bf16
// ---------------------------------------------------------------------------
__global__ __launch_bounds__(256, 2) void gemm1_enc(
    const float* __restrict__ X, const float* __restrict__ We,
    const float* __restrict__ be, __bf16* __restrict__ Fout)
{
    __shared__ __bf16 As[BM * ROWE];
    __shared__ __bf16 Bs[BN * ROWE];

    // XCD swizzle: xcd = bid&7 owns n-panels [xcd*32, xcd*32+32); within an
    // XCD the 8 m-sharers of a panel are adjacent -> panel read once per XCD.
    const int bid = blockIdx.x;            // 0..2047
    const int xcd = bid & 7;
    const int j   = bid >> 3;              // 0..255
    const int m0  = (j & 7) * BM;
    const int n0  = (xcd * 32 + (j >> 3)) * BN;

    const int tid = threadIdx.x;
    const int lane = tid & 63;
    const int w  = tid >> 6;
    const int wr = w >> 1, wc = w & 1;
    const int g  = lane >> 4;         // k-group 0..3
    const int r  = lane & 15;

    // A staging: thread owns (m=am, k-half=ah*16..+15) -> 4 f32x4 reads
    const int am = tid >> 1;          // 0..127
    const int ah = tid & 1;
    // B staging: thread owns one n column, k-range bc2*16..+15 -> 16 scalar reads
    const int bn  = tid & 127;
    const int bc2 = tid >> 7;         // 0 or 1

    f32x4 acc[4][4] = {};
    f32x4 aP[4];
    float bP[16];

    const float* Aptr = X + (size_t)m0 * K1;
    const float* Bptr = We + n0 + bn;

    auto loadA = [&](int k0) {
        #pragma unroll
        for (int q = 0; q < 4; ++q)
            aP[q] = *(const f32x4*)(Aptr + (size_t)am*K1 + k0 + ah*16 + q*4);
    };
    auto loadB = [&](int k0) {
        #pragma unroll
        for (int kk = 0; kk < 16; ++kk)
            bP[kk] = Bptr[(size_t)(k0 + bc2*16 + kk) * F_];
    };
    auto stageA = [&]() {
        bf16x8 v0, v1;
        #pragma unroll
        for (int e = 0; e < 4; ++e) {
            v0[e]   = (__bf16)aP[0][e];  v0[e+4] = (__bf16)aP[1][e];
            v1[e]   = (__bf16)aP[2][e];  v1[e+4] = (__bf16)aP[3][e];
        }
        *(bf16x8*)&As[am*ROWE + (ah*2  )*8] = v0;
        *(bf16x8*)&As[am*ROWE + (ah*2+1)*8] = v1;
    };
    auto stageB = [&]() {
        bf16x8 v0, v1;
        #pragma unroll
        for (int e = 0; e < 8; ++e) {
            v0[e] = (__bf16)bP[e];
            v1[e] = (__bf16)bP[8+e];
        }
        *(bf16x8*)&Bs[bn*ROWE + (bc2*2  )*8] = v0;
        *(bf16x8*)&Bs[bn*ROWE + (bc2*2+1)*8] = v1;
    };

    // loop-invariant fragment addresses
    int aOff[4], bOff[4];
    #pragma unroll
    for (int i = 0; i < 4; ++i) aOff[i] = (wr*64 + i*16 + r)*ROWE + g*8;
    #pragma unroll
    for (int jj = 0; jj < 4; ++jj) bOff[jj] = (wc*64 + jj*16 + r)*ROWE + g*8;

    loadA(0); loadB(0);
    for (int k0 = 0; k0 < K1; k0 += BK) {
        stageA(); stageB();
        __syncthreads();
        if (k0 + BK < K1) { loadA(k0 + BK); loadB(k0 + BK); }

        bf16x8 a[4], b[4];
        #pragma unroll
        for (int i = 0; i < 4; ++i) a[i] = *(const bf16x8*)&As[aOff[i]];
        #pragma unroll
        for (int jj = 0; jj < 4; ++jj) b[jj] = *(const bf16x8*)&Bs[bOff[jj]];
        #pragma unroll
        for (int i = 0; i < 4; ++i)
            #pragma unroll
            for (int jj = 0; jj < 4; ++jj)
                acc[i][jj] = __builtin_amdgcn_mfma_f32_16x16x32_bf16(
                    a[i], b[jj], acc[i][jj], 0, 0, 0);
        __syncthreads();
    }

    // epilogue: relu(acc + b_enc[col]) -> bf16
    #pragma unroll
    for (int jj = 0; jj < 4; ++jj) {
        int col = n0 + wc*64 + jj*16 + r;
        float bv = be[col];
        #pragma unroll
        for (int i = 0; i < 4; ++i) {
            #pragma unroll
            for (int v = 0; v < 4; ++v) {
                int row = m0 + wr*64 + i*16 + g*4 + v;
                float z = acc[i][jj][v] + bv;
                z = z > 0.f ? z : 0.f;
                Fout[(size_t)row * F_ + col] = (__bf16)z;
            }
        }
    }
}

// ---------------------------------------------------------------------------
// GEMM2 (split-K): Cp[s] = f[M,KC-chunk] @ W_dec-chunk, fp32 partials
// A (f, bf16) staged via global_load_lds; B (W_dec) via register transpose.
// ---------------------------------------------------------------------------
__global__ __launch_bounds__(256, 2) void gemm2_dec(
    const __bf16* __restrict__ Fin, const float* __restrict__ Wd,
    float* __restrict__ Cp)
{
    __shared__ __bf16 As2[BM * BK];        // unpadded: global_load_lds target
    __shared__ __bf16 Bs[BN * ROWE];

    // swizzle: xcd owns 8 (n,s) panel-pairs; m-sharers adjacent within xcd
    const int bid = blockIdx.x;            // 0..511
    const int xcd = bid & 7;
    const int j   = bid >> 3;              // 0..63
    const int m0  = (j & 7) * BM;
    const int pair = xcd * 8 + (j >> 3);   // 0..63
    const int s   = pair & 3;
    const int n0  = (pair >> 2) * BN;
    const int kbase = s * KC;

    const int tid = threadIdx.x;
    const int lane = tid & 63;
    const int w  = tid >> 6;
    const int wr = w >> 1, wc = w & 1;
    const int g  = lane >> 4;
    const int r  = lane & 15;

    const int bn  = tid & 127;
    const int bc2 = tid >> 7;

    f32x4 acc[4][4] = {};
    float bP[16];

    const int ldec = n0 >> 10;
    const float* Bptr = Wd + (size_t)ldec * F_ * D_ + (n0 & (D_-1)) + bn;
    const __bf16* Aptr = Fin + (size_t)m0 * F_ + kbase;

    auto loadB = [&](int k0) {
        #pragma unroll
        for (int kk = 0; kk < 16; ++kk)
            bP[kk] = Bptr[(size_t)(kbase + k0 + bc2*16 + kk) * D_];
    };
    auto stageB = [&]() {
        bf16x8 v0, v1;
        #pragma unroll
        for (int e = 0; e < 8; ++e) {
            v0[e] = (__bf16)bP[e];
            v1[e] = (__bf16)bP[8+e];
        }
        *(bf16x8*)&Bs[bn*ROWE + (bc2*2  )*8] = v0;
        *(bf16x8*)&Bs[bn*ROWE + (bc2*2+1)*8] = v1;
    };

    int aOff[4], bOff[4];
    #pragma unroll
    for (int i = 0; i < 4; ++i) aOff[i] = (wr*64 + i*16 + r)*BK + g*8;
    #pragma unroll
    for (int jj = 0; jj < 4; ++jj) bOff[jj] = (wc*64 + jj*16 + r)*ROWE + g*8;

    loadB(0);
    for (int k0 = 0; k0 < KC; k0 += BK) {
        // async A stage: 512 chunks of 16B, lane-ordered (wave-uniform base + lane*16)
        #pragma unroll
        for (int p = 0; p < 2; ++p) {
            int ch = p*256 + tid;
            int m = ch >> 2, c = ch & 3;
            glds16(Aptr + (size_t)m*F_ + k0 + c*8, &As2[ch*8]);
        }
        stageB();
        __syncthreads();                  // drains glds (vmcnt) + ds writes
        if (k0 + BK < KC) loadB(k0 + BK);

        bf16x8 a[4], b[4];
        #pragma unroll
        for (int i = 0; i < 4; ++i) a[i] = *(const bf16x8*)&As2[aOff[i]];
        #pragma unroll
        for (int jj = 0; jj < 4; ++jj) b[jj] = *(const bf16x8*)&Bs[bOff[jj]];
        #pragma unroll
        for (int i = 0; i < 4; ++i)
            #pragma unroll
            for (int jj = 0; jj < 4; ++jj)
                acc[i][jj] = __builtin_amdgcn_mfma_f32_16x16x32_bf16(
                    a[i], b[jj], acc[i][jj], 0, 0, 0);
        __syncthreads();
    }

    #pragma unroll
    for (int jj = 0; jj < 4; ++jj) {
        int col = n0 + wc*64 + jj*16 + r;
        #pragma unroll
        for (int i = 0; i < 4; ++i) {
            #pragma unroll
            for (int v = 0; v < 4; ++v) {
                int row = m0 + wr*64 + i*16 + g*4 + v;
                Cp[((size_t)s*M_ + row)*N2 + col] = acc[i][jj][v];
            }
        }
    }
}

// ---------------------------------------------------------------------------
// Reduce: out[m][n] = sum_s Cp[s][m][n] + b_dec[n]
// ---------------------------------------------------------------------------
__global__ __launch_bounds__(256) void reduce_add(
    const float* __restrict__ Cp, const float* __restrict__ bd,
    float* __restrict__ out)
{
    const size_t idx = ((size_t)blockIdx.x * 256 + threadIdx.x) * 4;
    f32x4 acc = {};
    #pragma unroll
    for (int s = 0; s < SPLITK; ++s) {
        f32x4 c = *(const f32x4*)(Cp + (size_t)s * M_ * N2 + idx);
        acc += c;
    }
    f32x4 b = *(const f32x4*)(bd + (idx & (N2 - 1)));
    *(f32x4*)(out + idx) = acc + b;
}

// ---------------------------------------------------------------------------
extern "C" void kernel_launch(void* const* d_in, const int* in_sizes, int n_in,
                              void* d_out, int out_size, void* d_ws, size_t ws_size,
                              hipStream_t stream) {
    const float* x  = (const float*)d_in[0];
    const float* We = (const float*)d_in[1];
    const float* be = (const float*)d_in[2];
    const float* Wd = (const float*)d_in[3];
    const float* bd = (const float*)d_in[4];
    float* out = (float*)d_out;

    // ws layout: f (bf16, 64MB) | Cp (fp32, SPLITK*M*N2 = 32MB)
    __bf16* f  = (__bf16*)d_ws;
    float*  Cp = (float*)((char*)d_ws + (size_t)M_ * F_ * sizeof(__bf16));

    gemm1_enc<<<dim3((M_/BM)*(F_/BN)), 256, 0, stream>>>(x, We, be, f);
    gemm2_dec<<<dim3((M_/BM)*(N2/BN)*SPLITK), 256, 0, stream>>>(f, Wd, Cp);
    reduce_add<<<dim3((M_*(size_t)N2)/(4*256)), 256, 0, stream>>>(Cp, bd, out);
}